// Round 7
// baseline (564.469 us; speedup 1.0000x reference)
//
#include <hip/hip_runtime.h>
#include <stdint.h>

// R7: latency-bound fix (R6: 8 waves/CU, 20 cyc/inst effective, all pipes idle).
// - 512 thr/block (8 waves), wave = 2 row-tiles x 4 col-tiles -> acc 32 regs,
//   fits __launch_bounds__(512,4) 128-reg budget -> 16 waves/CU (2x TLP).
// - ping-pong act (2x32KB): no barrier between kloop reads and epilogue writes;
//   barriers 10 -> 6.
// - scalar phases spread over 512 threads.

#define NRAYS 4096

typedef unsigned short u16;
typedef __attribute__((ext_vector_type(8))) short short8;
typedef __attribute__((ext_vector_type(4))) float f32x4;

__device__ __forceinline__ u16 f2bf(float f) {
  union { float f; uint32_t i; } v; v.f = f;
  return (u16)((v.i + 0x7FFFu + ((v.i >> 16) & 1u)) >> 16);
}
__device__ __forceinline__ float bf2f(u16 u) {
  union { uint32_t i; float f; } v; v.i = ((uint32_t)u) << 16; return v.f;
}

// ---------------- weight transpose + fp32->bf16 convert into workspace ----------------
// ws (bf16 elems): W2t [256n][256k] @0, W3t [256n][256k] @65536, W4t [128n][256k] @131072
__global__ void pack_weights(const float* __restrict__ W2, const float* __restrict__ W3,
                             const float* __restrict__ W4, u16* __restrict__ ws) {
  int idx = blockIdx.x * 256 + threadIdx.x;   // grid covers exactly 163840
  float v;
  if (idx < 65536) {
    int n = idx >> 8, k = idx & 255;
    v = W2[k * 256 + n];
  } else if (idx < 131072) {
    int o = idx - 65536, n = o >> 8, k = o & 255;
    v = W3[k * 256 + n];
  } else {
    int o = idx - 131072, n = o >> 8, k = o & 255;
    v = W4[k * 128 + n];
  }
  ws[idx] = f2bf(v);
}

#define MFMA __builtin_amdgcn_mfma_f32_16x16x32_bf16
#define ZER4 (f32x4){0.f, 0.f, 0.f, 0.f}

// K-step, 2 row-tiles x 4 col-tiles: 4 B (global), 2 A (LDS), 8 MFMA
#define KSTEP42(rd, sq_) do {                                               \
    const int sq = (sq_);                                                   \
    short8 bv0 = *(const short8*)(bp0 + sq * 8);                            \
    short8 bv1 = *(const short8*)(bp1 + sq * 8);                            \
    short8 bv2 = *(const short8*)(bp2 + sq * 8);                            \
    short8 bv3 = *(const short8*)(bp3 + sq * 8);                            \
    short8 av0 = *(const short8*)((rd) + m0 * 256 + ((sq ^ (m0 & 31)) << 3)); \
    short8 av1 = *(const short8*)((rd) + m1 * 256 + ((sq ^ (m1 & 31)) << 3)); \
    c00 = MFMA(av0, bv0, c00, 0, 0, 0); c10 = MFMA(av1, bv0, c10, 0, 0, 0); \
    c01 = MFMA(av0, bv1, c01, 0, 0, 0); c11 = MFMA(av1, bv1, c11, 0, 0, 0); \
    c02 = MFMA(av0, bv2, c02, 0, 0, 0); c12 = MFMA(av1, bv2, c12, 0, 0, 0); \
    c03 = MFMA(av0, bv3, c03, 0, 0, 0); c13 = MFMA(av1, bv3, c13, 0, 0, 0); \
  } while (0)

// K-step, 2 row-tiles x 2 col-tiles (layer 4): 2 B, 2 A, 4 MFMA
#define KSTEP22(rd, sq_) do {                                               \
    const int sq = (sq_);                                                   \
    short8 bv0 = *(const short8*)(bp0 + sq * 8);                            \
    short8 bv1 = *(const short8*)(bp1 + sq * 8);                            \
    short8 av0 = *(const short8*)((rd) + m0 * 256 + ((sq ^ (m0 & 31)) << 3)); \
    short8 av1 = *(const short8*)((rd) + m1 * 256 + ((sq ^ (m1 & 31)) << 3)); \
    c00 = MFMA(av0, bv0, c00, 0, 0, 0); c10 = MFMA(av1, bv0, c10, 0, 0, 0); \
    c01 = MFMA(av0, bv1, c01, 0, 0, 0); c11 = MFMA(av1, bv1, c11, 0, 0, 0); \
  } while (0)

// store one 16x16 C-tile: absolute row-tile mta, column ng, relu(+addv), swizzled
#define EPIC(dst, CV, mta, ng, addv) do {                                   \
    int su_ = ((ng) >> 3), so_ = ((ng) & 7);                                \
    _Pragma("unroll")                                                       \
    for (int r = 0; r < 4; r++) {                                           \
      int mm = (mta) * 16 + quad * 4 + r;                                   \
      (dst)[mm * 256 + ((su_ ^ (mm & 31)) << 3) + so_] =                    \
          f2bf(fmaxf((CV)[r] + (addv), 0.f));                               \
    }                                                                       \
  } while (0)

__global__ void __launch_bounds__(512, 4) nerf_fused(
    const float* __restrict__ rays_o, const float* __restrict__ rays_d,
    const float* __restrict__ t_rand,
    const float* __restrict__ W1, const float* __restrict__ b1,
    const float* __restrict__ b2, const float* __restrict__ b3,
    const float* __restrict__ Wd, const float* __restrict__ bd,
    const float* __restrict__ W4, const float* __restrict__ b4,
    const float* __restrict__ W5, const float* __restrict__ b5,
    const u16* __restrict__ wpack, float* __restrict__ out) {
  __shared__ __align__(16) u16 actA[64 * 256];   // 32 KB ping
  __shared__ __align__(16) u16 actB[64 * 256];   // 32 KB pong
  __shared__ float zv[64];
  __shared__ float dist[64];
  __shared__ float dens[64];
  __shared__ float rgbL[64 * 4];
  __shared__ float vdirL[4];
  __shared__ float w5L[384];
  __shared__ float b5L[4];

  const int t = threadIdx.x;
  const int lane = t & 63;
  const int wv = t >> 6;        // 0..7
  const int quad = lane >> 4;
  const int l15 = lane & 15;
  const int rh = wv >> 2;       // 0..1 : row half (rows rh*32..+31)
  const int cq = wv & 3;        // 0..3 : col quarter
  const int ray = blockIdx.x;
  const int m0 = rh * 32 + l15, m1 = m0 + 16;

  // ---- setup ----
  if (t < 64) {
    int j = t;
    float fj = (float)j;
    float zj = 0.5f + 2.0f * (fj / 63.0f);
    float lower = (j == 0)  ? zj : 0.5f * (zj + (0.5f + 2.0f * ((fj - 1.0f) / 63.0f)));
    float upper = (j == 63) ? zj : 0.5f * (zj + (0.5f + 2.0f * ((fj + 1.0f) / 63.0f)));
    float tr = t_rand[ray * 64 + j];
    zv[j] = lower + (upper - lower) * tr;
  } else if (t < 448) {
    w5L[t - 64] = W5[t - 64];          // 384 elems
  }
  if (t < 3) b5L[t] = b5[t];
  if (t == 0) {
    float dx = rays_d[ray * 3 + 0];
    float dy = rays_d[ray * 3 + 1];
    float dz = rays_d[ray * 3 + 2];
    float nrm = sqrtf(dx * dx + dy * dy + dz * dz) + 1e-8f;
    vdirL[0] = dx / nrm; vdirL[1] = dy / nrm; vdirL[2] = dz / nrm;
  }
  __syncthreads();                     // B1

  if (t < 64) dist[t] = (t < 63) ? (zv[t + 1] - zv[t]) : 1e10f;

  // ---- layer 1: h1 = relu(pts@W1 + b1) -> actA ----
  {
    int m = t >> 3, p = t & 7;         // 8 threads/row, 32 cols each
    float zm = zv[m];
    float px = rays_o[ray * 3 + 0] + rays_d[ray * 3 + 0] * zm;
    float py = rays_o[ray * 3 + 1] + rays_d[ray * 3 + 1] * zm;
    float pz = rays_o[ray * 3 + 2] + rays_d[ray * 3 + 2] * zm;
#pragma unroll
    for (int kk = 0; kk < 32; kk += 8) {
      int k0 = p * 32 + kk;
      f32x4 bva = *(const f32x4*)(b1 + k0);
      f32x4 bvb = *(const f32x4*)(b1 + k0 + 4);
      f32x4 w0a = *(const f32x4*)(W1 + k0);
      f32x4 w0b = *(const f32x4*)(W1 + k0 + 4);
      f32x4 w1a = *(const f32x4*)(W1 + 256 + k0);
      f32x4 w1b = *(const f32x4*)(W1 + 256 + k0 + 4);
      f32x4 w2a = *(const f32x4*)(W1 + 512 + k0);
      f32x4 w2b = *(const f32x4*)(W1 + 512 + k0 + 4);
      f32x4 sa = bva + px * w0a + py * w1a + pz * w2a;
      f32x4 sb = bvb + px * w0b + py * w1b + pz * w2b;
      short8 res;
      res[0] = (short)f2bf(fmaxf(sa[0], 0.f));
      res[1] = (short)f2bf(fmaxf(sa[1], 0.f));
      res[2] = (short)f2bf(fmaxf(sa[2], 0.f));
      res[3] = (short)f2bf(fmaxf(sa[3], 0.f));
      res[4] = (short)f2bf(fmaxf(sb[0], 0.f));
      res[5] = (short)f2bf(fmaxf(sb[1], 0.f));
      res[6] = (short)f2bf(fmaxf(sb[2], 0.f));
      res[7] = (short)f2bf(fmaxf(sb[3], 0.f));
      int u = (k0 >> 3) ^ (m & 31);
      *(short8*)(actA + m * 256 + u * 8) = res;
    }
  }
  __syncthreads();                     // B2: actA (h1) ready

  // ---- layers 2 & 3: ping-pong, 1 barrier each ----
#pragma unroll 1
  for (int L = 0; L < 2; L++) {
    const u16* wB = wpack + L * 65536;
    const float* bb = (L == 0) ? b2 : b3;
    const u16* rd = (L == 0) ? actA : actB;
    u16*       wr = (L == 0) ? actB : actA;
    const u16* bp0 = wB + (cq * 64 +  0 + l15) * 256;
    const u16* bp1 = wB + (cq * 64 + 16 + l15) * 256;
    const u16* bp2 = wB + (cq * 64 + 32 + l15) * 256;
    const u16* bp3 = wB + (cq * 64 + 48 + l15) * 256;
    f32x4 c00 = ZER4, c01 = ZER4, c02 = ZER4, c03 = ZER4;
    f32x4 c10 = ZER4, c11 = ZER4, c12 = ZER4, c13 = ZER4;
#pragma unroll
    for (int kc = 0; kc < 8; kc++) KSTEP42(rd, kc * 4 + quad);
    // epilogue writes the other buffer: no barrier needed before it
    {
      int ng0 = cq * 64 + l15;
      float bi0 = bb[ng0], bi1 = bb[ng0 + 16], bi2 = bb[ng0 + 32], bi3 = bb[ng0 + 48];
      int t0 = rh * 2, t1 = rh * 2 + 1;
      EPIC(wr, c00, t0, ng0, bi0);      EPIC(wr, c10, t1, ng0, bi0);
      EPIC(wr, c01, t0, ng0 + 16, bi1); EPIC(wr, c11, t1, ng0 + 16, bi1);
      EPIC(wr, c02, t0, ng0 + 32, bi2); EPIC(wr, c12, t1, ng0 + 32, bi2);
      EPIC(wr, c03, t0, ng0 + 48, bi3); EPIC(wr, c13, t1, ng0 + 48, bi3);
    }
    __syncthreads();                   // B3/B4: new act ready
  }

  // ---- density: fp32 dot(h3=actA, Wd) ----
  {
    int m = t >> 3, p = t & 7;
    float s = 0.f;
#pragma unroll
    for (int kk = 0; kk < 32; kk += 8) {
      int k0 = p * 32 + kk;
      short8 h = *(const short8*)(actA + m * 256 + (((k0 >> 3) ^ (m & 31)) << 3));
      f32x4 wa = *(const f32x4*)(Wd + k0);
      f32x4 wb = *(const f32x4*)(Wd + k0 + 4);
      s += bf2f((u16)h[0]) * wa[0] + bf2f((u16)h[1]) * wa[1]
         + bf2f((u16)h[2]) * wa[2] + bf2f((u16)h[3]) * wa[3]
         + bf2f((u16)h[4]) * wb[0] + bf2f((u16)h[5]) * wb[1]
         + bf2f((u16)h[6]) * wb[2] + bf2f((u16)h[7]) * wb[3];
    }
    s += __shfl_xor(s, 1);
    s += __shfl_xor(s, 2);
    s += __shfl_xor(s, 4);
    if (p == 0) dens[m] = s + bd[0];
  }

  // ---- layer 4: h4 = relu(h3@W4[:256] + vdir@W4[256:259] + b4) -> actB ----
  {
    const u16* wB = wpack + 131072;
    const u16* bp0 = wB + (cq * 32 +  0 + l15) * 256;
    const u16* bp1 = wB + (cq * 32 + 16 + l15) * 256;
    f32x4 c00 = ZER4, c01 = ZER4;
    f32x4 c10 = ZER4, c11 = ZER4;
#pragma unroll
    for (int kc = 0; kc < 8; kc++) KSTEP22(actA, kc * 4 + quad);
    {
      float v0 = vdirL[0], v1 = vdirL[1], v2 = vdirL[2];
      int ng0 = cq * 32 + l15;
      float ad0 = b4[ng0] + v0 * W4[32768 + ng0] + v1 * W4[32896 + ng0] + v2 * W4[33024 + ng0];
      int ng1 = ng0 + 16;
      float ad1 = b4[ng1] + v0 * W4[32768 + ng1] + v1 * W4[32896 + ng1] + v2 * W4[33024 + ng1];
      int t0 = rh * 2, t1 = rh * 2 + 1;
      EPIC(actB, c00, t0, ng0, ad0); EPIC(actB, c10, t1, ng0, ad0);
      EPIC(actB, c01, t0, ng1, ad1); EPIC(actB, c11, t1, ng1, ad1);
    }
  }
  __syncthreads();                     // B5: actB (h4) + dens ready

  // ---- rgb = sigmoid(h4@W5 + b5) ----
  {
    int m = t >> 3, p = t & 7;         // 8 threads/row, 16 cols each
    float s0 = 0.f, s1 = 0.f, s2 = 0.f;
#pragma unroll
    for (int kk = 0; kk < 16; kk += 8) {
      int k0 = p * 16 + kk;
      short8 h = *(const short8*)(actB + m * 256 + (((k0 >> 3) ^ (m & 31)) << 3));
#pragma unroll
      for (int j = 0; j < 8; j++) {
        float hv = bf2f((u16)h[j]);
        int k = k0 + j;
        s0 += hv * w5L[k * 3 + 0];
        s1 += hv * w5L[k * 3 + 1];
        s2 += hv * w5L[k * 3 + 2];
      }
    }
    s0 += __shfl_xor(s0, 1); s0 += __shfl_xor(s0, 2); s0 += __shfl_xor(s0, 4);
    s1 += __shfl_xor(s1, 1); s1 += __shfl_xor(s1, 2); s1 += __shfl_xor(s1, 4);
    s2 += __shfl_xor(s2, 1); s2 += __shfl_xor(s2, 2); s2 += __shfl_xor(s2, 4);
    if (p == 0) {
      rgbL[m * 4 + 0] = 1.f / (1.f + __expf(-(s0 + b5L[0])));
      rgbL[m * 4 + 1] = 1.f / (1.f + __expf(-(s1 + b5L[1])));
      rgbL[m * 4 + 2] = 1.f / (1.f + __expf(-(s2 + b5L[2])));
    }
  }
  __syncthreads();                     // B6: rgbL ready

  // ---- alpha compositing: wave 0 ----
  if (t < 64) {
    int j = t;
    float alpha = 1.f - __expf(-fmaxf(dens[j], 0.f) * dist[j]);
    float v = 1.f - alpha + 1e-10f;
    float pscan = v;
#pragma unroll
    for (int d = 1; d < 64; d <<= 1) {
      float o = __shfl_up(pscan, d);
      if (j >= d) pscan *= o;
    }
    float T = __shfl_up(pscan, 1);
    if (j == 0) T = 1.f;
    float w = alpha * T;
    float r0 = w * rgbL[j * 4 + 0];
    float r1 = w * rgbL[j * 4 + 1];
    float r2 = w * rgbL[j * 4 + 2];
    float dp = w * zv[j];
    float ac = w;
#pragma unroll
    for (int d = 32; d; d >>= 1) {
      r0 += __shfl_down(r0, d);
      r1 += __shfl_down(r1, d);
      r2 += __shfl_down(r2, d);
      dp += __shfl_down(dp, d);
      ac += __shfl_down(ac, d);
    }
    if (j == 0) {
      float bg = 1.f - ac;
      out[ray * 3 + 0] = r0 + bg;
      out[ray * 3 + 1] = r1 + bg;
      out[ray * 3 + 2] = r2 + bg;
      out[NRAYS * 3 + ray] = dp;
      out[NRAYS * 4 + ray] = ac;
    }
  }
}

extern "C" void kernel_launch(void* const* d_in, const int* in_sizes, int n_in,
                              void* d_out, int out_size, void* d_ws, size_t ws_size,
                              hipStream_t stream) {
  const float* rays_o = (const float*)d_in[0];
  const float* rays_d = (const float*)d_in[1];
  const float* t_rand = (const float*)d_in[2];
  const float* W1 = (const float*)d_in[3];
  const float* b1 = (const float*)d_in[4];
  const float* W2 = (const float*)d_in[5];
  const float* b2 = (const float*)d_in[6];
  const float* W3 = (const float*)d_in[7];
  const float* b3 = (const float*)d_in[8];
  const float* Wd = (const float*)d_in[9];
  const float* bd = (const float*)d_in[10];
  const float* W4 = (const float*)d_in[11];
  const float* b4 = (const float*)d_in[12];
  const float* W5 = (const float*)d_in[13];
  const float* b5 = (const float*)d_in[14];
  u16* wpack = (u16*)d_ws;
  float* out = (float*)d_out;

  pack_weights<<<640, 256, 0, stream>>>(W2, W3, W4, wpack);
  nerf_fused<<<NRAYS, 512, 0, stream>>>(rays_o, rays_d, t_rand, W1, b1, b2, b3,
                                        Wd, bd, W4, b4, W5, b5, wpack, out);
}

// Round 8
// 526.545 us; speedup vs baseline: 1.0720x; 1.0720x over previous
//
#include <hip/hip_runtime.h>
#include <stdint.h>

// R8: R6 structure exactly, one variable: __launch_bounds__(256,3) -> 170-reg
// budget (acc 64 AGPR + ~106 arch). R6 (256,2) = 192 regs/wave caps HW at
// 2 waves/SIMD (8 waves/CU); R7 proved 128-reg budget spills. 170 is the
// untested middle: 12 waves/CU, 3 independent blocks for phase overlap.
// Spill sentinel: WRITE_SIZE (<1 MB good; >50 MB = revert).

#define NRAYS 4096

typedef unsigned short u16;
typedef __attribute__((ext_vector_type(8))) short short8;
typedef __attribute__((ext_vector_type(4))) float f32x4;

__device__ __forceinline__ u16 f2bf(float f) {
  union { float f; uint32_t i; } v; v.f = f;
  return (u16)((v.i + 0x7FFFu + ((v.i >> 16) & 1u)) >> 16);
}
__device__ __forceinline__ float bf2f(u16 u) {
  union { uint32_t i; float f; } v; v.i = ((uint32_t)u) << 16; return v.f;
}

// ---------------- weight transpose + fp32->bf16 convert into workspace ----------------
// ws (bf16 elems): W2t [256n][256k] @0, W3t [256n][256k] @65536, W4t [128n][256k] @131072
__global__ void pack_weights(const float* __restrict__ W2, const float* __restrict__ W3,
                             const float* __restrict__ W4, u16* __restrict__ ws) {
  int idx = blockIdx.x * 256 + threadIdx.x;   // grid covers exactly 163840
  float v;
  if (idx < 65536) {
    int n = idx >> 8, k = idx & 255;
    v = W2[k * 256 + n];
  } else if (idx < 131072) {
    int o = idx - 65536, n = o >> 8, k = o & 255;
    v = W3[k * 256 + n];
  } else {
    int o = idx - 131072, n = o >> 8, k = o & 255;
    v = W4[k * 128 + n];
  }
  ws[idx] = f2bf(v);
}

#define MFMA __builtin_amdgcn_mfma_f32_16x16x32_bf16
#define ZER4 (f32x4){0.f, 0.f, 0.f, 0.f}

// one K-step (K=32) of the 4-col-tile GEMM: 4 B loads (global), 4 A loads (LDS), 16 MFMA
#define KSTEP4(sq_) do {                                                     \
    const int sq = (sq_);                                                    \
    short8 bv0 = *(const short8*)(bp0 + sq * 8);                             \
    short8 bv1 = *(const short8*)(bp1 + sq * 8);                             \
    short8 bv2 = *(const short8*)(bp2 + sq * 8);                             \
    short8 bv3 = *(const short8*)(bp3 + sq * 8);                             \
    short8 av0 = *(const short8*)(act + m0 * 256 + ((sq ^ (m0 & 31)) << 3)); \
    short8 av1 = *(const short8*)(act + m1 * 256 + ((sq ^ (m1 & 31)) << 3)); \
    short8 av2 = *(const short8*)(act + m2 * 256 + ((sq ^ (m2 & 31)) << 3)); \
    short8 av3 = *(const short8*)(act + m3 * 256 + ((sq ^ (m3 & 31)) << 3)); \
    c00 = MFMA(av0, bv0, c00, 0, 0, 0); c10 = MFMA(av1, bv0, c10, 0, 0, 0);  \
    c20 = MFMA(av2, bv0, c20, 0, 0, 0); c30 = MFMA(av3, bv0, c30, 0, 0, 0);  \
    c01 = MFMA(av0, bv1, c01, 0, 0, 0); c11 = MFMA(av1, bv1, c11, 0, 0, 0);  \
    c21 = MFMA(av2, bv1, c21, 0, 0, 0); c31 = MFMA(av3, bv1, c31, 0, 0, 0);  \
    c02 = MFMA(av0, bv2, c02, 0, 0, 0); c12 = MFMA(av1, bv2, c12, 0, 0, 0);  \
    c22 = MFMA(av2, bv2, c22, 0, 0, 0); c32 = MFMA(av3, bv2, c32, 0, 0, 0);  \
    c03 = MFMA(av0, bv3, c03, 0, 0, 0); c13 = MFMA(av1, bv3, c13, 0, 0, 0);  \
    c23 = MFMA(av2, bv3, c23, 0, 0, 0); c33 = MFMA(av3, bv3, c33, 0, 0, 0);  \
  } while (0)

// one K-step of the 2-col-tile GEMM (layer 4)
#define KSTEP2(sq_) do {                                                     \
    const int sq = (sq_);                                                    \
    short8 bv0 = *(const short8*)(bp0 + sq * 8);                             \
    short8 bv1 = *(const short8*)(bp1 + sq * 8);                             \
    short8 av0 = *(const short8*)(act + m0 * 256 + ((sq ^ (m0 & 31)) << 3)); \
    short8 av1 = *(const short8*)(act + m1 * 256 + ((sq ^ (m1 & 31)) << 3)); \
    short8 av2 = *(const short8*)(act + m2 * 256 + ((sq ^ (m2 & 31)) << 3)); \
    short8 av3 = *(const short8*)(act + m3 * 256 + ((sq ^ (m3 & 31)) << 3)); \
    c00 = MFMA(av0, bv0, c00, 0, 0, 0); c10 = MFMA(av1, bv0, c10, 0, 0, 0);  \
    c20 = MFMA(av2, bv0, c20, 0, 0, 0); c30 = MFMA(av3, bv0, c30, 0, 0, 0);  \
    c01 = MFMA(av0, bv1, c01, 0, 0, 0); c11 = MFMA(av1, bv1, c11, 0, 0, 0);  \
    c21 = MFMA(av2, bv1, c21, 0, 0, 0); c31 = MFMA(av3, bv1, c31, 0, 0, 0);  \
  } while (0)

// store one 16x16 C-tile (named f32x4 CV), row-tile mt, column ng, into swizzled act
#define EPIC(CV, mt, ng, addv) do {                                          \
    int su_ = ((ng) >> 3), so_ = ((ng) & 7);                                 \
    _Pragma("unroll")                                                        \
    for (int r = 0; r < 4; r++) {                                            \
      int mm = (mt) * 16 + quad * 4 + r;                                     \
      act[mm * 256 + ((su_ ^ (mm & 31)) << 3) + so_] =                       \
          f2bf(fmaxf((CV)[r] + (addv), 0.f));                                \
    }                                                                        \
  } while (0)

__global__ void __launch_bounds__(256, 3) nerf_fused(
    const float* __restrict__ rays_o, const float* __restrict__ rays_d,
    const float* __restrict__ t_rand,
    const float* __restrict__ W1, const float* __restrict__ b1,
    const float* __restrict__ b2, const float* __restrict__ b3,
    const float* __restrict__ Wd, const float* __restrict__ bd,
    const float* __restrict__ W4, const float* __restrict__ b4,
    const float* __restrict__ W5, const float* __restrict__ b5,
    const u16* __restrict__ wpack, float* __restrict__ out) {
  __shared__ u16   act[64 * 256];    // 32 KB, XOR-swizzled slots
  __shared__ float zv[64];
  __shared__ float dist[64];
  __shared__ float dens[64];
  __shared__ float rgbL[64 * 4];
  __shared__ float vdirL[4];
  __shared__ float w5L[384];
  __shared__ float b5L[4];

  const int t = threadIdx.x;
  const int lane = t & 63;
  const int wv = t >> 6;        // 0..3
  const int quad = lane >> 4;
  const int l15 = lane & 15;
  const int ray = blockIdx.x;
  const int m0 = l15, m1 = l15 + 16, m2 = l15 + 32, m3 = l15 + 48;

  // ---- setup ----
  if (t < 64) {
    int j = t;
    float fj = (float)j;
    float zj = 0.5f + 2.0f * (fj / 63.0f);
    float lower = (j == 0)  ? zj : 0.5f * (zj + (0.5f + 2.0f * ((fj - 1.0f) / 63.0f)));
    float upper = (j == 63) ? zj : 0.5f * (zj + (0.5f + 2.0f * ((fj + 1.0f) / 63.0f)));
    float tr = t_rand[ray * 64 + j];
    zv[j] = lower + (upper - lower) * tr;
  } else {
    int idx = t - 64;                 // 0..191
    w5L[idx] = W5[idx];
    w5L[idx + 192] = W5[idx + 192];
  }
  if (t < 3) b5L[t] = b5[t];
  if (t == 0) {
    float dx = rays_d[ray * 3 + 0];
    float dy = rays_d[ray * 3 + 1];
    float dz = rays_d[ray * 3 + 2];
    float nrm = sqrtf(dx * dx + dy * dy + dz * dz) + 1e-8f;
    vdirL[0] = dx / nrm; vdirL[1] = dy / nrm; vdirL[2] = dz / nrm;
  }
  __syncthreads();

  if (t < 64) dist[t] = (t < 63) ? (zv[t + 1] - zv[t]) : 1e10f;

  // ---- layer 1: h1 = relu(pts@W1 + b1) -> act (pure vector ops) ----
  {
    int m = t >> 2, p = t & 3;
    float zm = zv[m];
    float px = rays_o[ray * 3 + 0] + rays_d[ray * 3 + 0] * zm;
    float py = rays_o[ray * 3 + 1] + rays_d[ray * 3 + 1] * zm;
    float pz = rays_o[ray * 3 + 2] + rays_d[ray * 3 + 2] * zm;
#pragma unroll
    for (int kk = 0; kk < 64; kk += 8) {
      int k0 = p * 64 + kk;
      f32x4 bva = *(const f32x4*)(b1 + k0);
      f32x4 bvb = *(const f32x4*)(b1 + k0 + 4);
      f32x4 w0a = *(const f32x4*)(W1 + k0);
      f32x4 w0b = *(const f32x4*)(W1 + k0 + 4);
      f32x4 w1a = *(const f32x4*)(W1 + 256 + k0);
      f32x4 w1b = *(const f32x4*)(W1 + 256 + k0 + 4);
      f32x4 w2a = *(const f32x4*)(W1 + 512 + k0);
      f32x4 w2b = *(const f32x4*)(W1 + 512 + k0 + 4);
      f32x4 sa = bva + px * w0a + py * w1a + pz * w2a;
      f32x4 sb = bvb + px * w0b + py * w1b + pz * w2b;
      short8 res;
      res[0] = (short)f2bf(fmaxf(sa[0], 0.f));
      res[1] = (short)f2bf(fmaxf(sa[1], 0.f));
      res[2] = (short)f2bf(fmaxf(sa[2], 0.f));
      res[3] = (short)f2bf(fmaxf(sa[3], 0.f));
      res[4] = (short)f2bf(fmaxf(sb[0], 0.f));
      res[5] = (short)f2bf(fmaxf(sb[1], 0.f));
      res[6] = (short)f2bf(fmaxf(sb[2], 0.f));
      res[7] = (short)f2bf(fmaxf(sb[3], 0.f));
      int u = (k0 >> 3) ^ (m & 31);
      *(short8*)(act + m * 256 + u * 8) = res;
    }
  }
  __syncthreads();

  // ---- layers 2 & 3: h = relu(h@W + b), K=256, N=256, B streamed from L2 ----
#pragma unroll 1
  for (int L = 0; L < 2; L++) {
    const u16* wB = wpack + L * 65536;
    const float* bb = (L == 0) ? b2 : b3;
    const u16* bp0 = wB + (wv * 64 +  0 + l15) * 256;
    const u16* bp1 = wB + (wv * 64 + 16 + l15) * 256;
    const u16* bp2 = wB + (wv * 64 + 32 + l15) * 256;
    const u16* bp3 = wB + (wv * 64 + 48 + l15) * 256;
    f32x4 c00 = ZER4, c01 = ZER4, c02 = ZER4, c03 = ZER4;
    f32x4 c10 = ZER4, c11 = ZER4, c12 = ZER4, c13 = ZER4;
    f32x4 c20 = ZER4, c21 = ZER4, c22 = ZER4, c23 = ZER4;
    f32x4 c30 = ZER4, c31 = ZER4, c32 = ZER4, c33 = ZER4;
#pragma unroll
    for (int kc = 0; kc < 8; kc++) KSTEP4(kc * 4 + quad);
    __syncthreads();               // all act reads done before in-place rewrite
    {
      int ng0 = wv * 64 + l15;
      float bi0 = bb[ng0], bi1 = bb[ng0 + 16], bi2 = bb[ng0 + 32], bi3 = bb[ng0 + 48];
      EPIC(c00, 0, ng0, bi0); EPIC(c10, 1, ng0, bi0);
      EPIC(c20, 2, ng0, bi0); EPIC(c30, 3, ng0, bi0);
      EPIC(c01, 0, ng0 + 16, bi1); EPIC(c11, 1, ng0 + 16, bi1);
      EPIC(c21, 2, ng0 + 16, bi1); EPIC(c31, 3, ng0 + 16, bi1);
      EPIC(c02, 0, ng0 + 32, bi2); EPIC(c12, 1, ng0 + 32, bi2);
      EPIC(c22, 2, ng0 + 32, bi2); EPIC(c32, 3, ng0 + 32, bi2);
      EPIC(c03, 0, ng0 + 48, bi3); EPIC(c13, 1, ng0 + 48, bi3);
      EPIC(c23, 2, ng0 + 48, bi3); EPIC(c33, 3, ng0 + 48, bi3);
    }
    __syncthreads();
  }

  // ---- density: fp32 dot(h3, Wd) ----
  {
    int m = t >> 2, p = t & 3;
    float s = 0.f;
#pragma unroll
    for (int kk = 0; kk < 64; kk += 8) {
      int k0 = p * 64 + kk;
      short8 h = *(const short8*)(act + m * 256 + (((k0 >> 3) ^ (m & 31)) << 3));
      f32x4 wa = *(const f32x4*)(Wd + k0);
      f32x4 wb = *(const f32x4*)(Wd + k0 + 4);
      s += bf2f((u16)h[0]) * wa[0] + bf2f((u16)h[1]) * wa[1]
         + bf2f((u16)h[2]) * wa[2] + bf2f((u16)h[3]) * wa[3]
         + bf2f((u16)h[4]) * wb[0] + bf2f((u16)h[5]) * wb[1]
         + bf2f((u16)h[6]) * wb[2] + bf2f((u16)h[7]) * wb[3];
    }
    s += __shfl_xor(s, 1);
    s += __shfl_xor(s, 2);
    if (p == 0) dens[m] = s + bd[0];
  }

  // ---- layer 4: h4 = relu(h3@W4[:256] + vdir@W4[256:259] + b4), N=128 ----
  {
    const u16* wB = wpack + 131072;
    const u16* bp0 = wB + (wv * 32 +  0 + l15) * 256;
    const u16* bp1 = wB + (wv * 32 + 16 + l15) * 256;
    f32x4 c00 = ZER4, c01 = ZER4;
    f32x4 c10 = ZER4, c11 = ZER4;
    f32x4 c20 = ZER4, c21 = ZER4;
    f32x4 c30 = ZER4, c31 = ZER4;
#pragma unroll
    for (int kc = 0; kc < 8; kc++) KSTEP2(kc * 4 + quad);
    __syncthreads();               // all h3 reads done (incl. density) before rewrite
    {
      float v0 = vdirL[0], v1 = vdirL[1], v2 = vdirL[2];
      int ng0 = wv * 32 + l15;
      float ad0 = b4[ng0] + v0 * W4[32768 + ng0] + v1 * W4[32896 + ng0] + v2 * W4[33024 + ng0];
      int ng1 = ng0 + 16;
      float ad1 = b4[ng1] + v0 * W4[32768 + ng1] + v1 * W4[32896 + ng1] + v2 * W4[33024 + ng1];
      EPIC(c00, 0, ng0, ad0); EPIC(c10, 1, ng0, ad0);
      EPIC(c20, 2, ng0, ad0); EPIC(c30, 3, ng0, ad0);
      EPIC(c01, 0, ng1, ad1); EPIC(c11, 1, ng1, ad1);
      EPIC(c21, 2, ng1, ad1); EPIC(c31, 3, ng1, ad1);
    }
  }
  __syncthreads();

  // ---- rgb = sigmoid(h4@W5 + b5) ----
  {
    int m = t >> 2, p = t & 3;
    float s0 = 0.f, s1 = 0.f, s2 = 0.f;
#pragma unroll
    for (int kk = 0; kk < 32; kk += 8) {
      int k0 = p * 32 + kk;
      short8 h = *(const short8*)(act + m * 256 + (((k0 >> 3) ^ (m & 31)) << 3));
#pragma unroll
      for (int j = 0; j < 8; j++) {
        float hv = bf2f((u16)h[j]);
        int k = k0 + j;
        s0 += hv * w5L[k * 3 + 0];
        s1 += hv * w5L[k * 3 + 1];
        s2 += hv * w5L[k * 3 + 2];
      }
    }
    s0 += __shfl_xor(s0, 1); s0 += __shfl_xor(s0, 2);
    s1 += __shfl_xor(s1, 1); s1 += __shfl_xor(s1, 2);
    s2 += __shfl_xor(s2, 1); s2 += __shfl_xor(s2, 2);
    if (p == 0) {
      rgbL[m * 4 + 0] = 1.f / (1.f + __expf(-(s0 + b5L[0])));
      rgbL[m * 4 + 1] = 1.f / (1.f + __expf(-(s1 + b5L[1])));
      rgbL[m * 4 + 2] = 1.f / (1.f + __expf(-(s2 + b5L[2])));
    }
  }
  __syncthreads();

  // ---- alpha compositing: wave 0 handles the block's single ray ----
  if (t < 64) {
    int j = t;
    float alpha = 1.f - __expf(-fmaxf(dens[j], 0.f) * dist[j]);
    float v = 1.f - alpha + 1e-10f;
    float pscan = v;
#pragma unroll
    for (int d = 1; d < 64; d <<= 1) {
      float o = __shfl_up(pscan, d);
      if (j >= d) pscan *= o;
    }
    float T = __shfl_up(pscan, 1);
    if (j == 0) T = 1.f;
    float w = alpha * T;
    float r0 = w * rgbL[j * 4 + 0];
    float r1 = w * rgbL[j * 4 + 1];
    float r2 = w * rgbL[j * 4 + 2];
    float dp = w * zv[j];
    float ac = w;
#pragma unroll
    for (int d = 32; d; d >>= 1) {
      r0 += __shfl_down(r0, d);
      r1 += __shfl_down(r1, d);
      r2 += __shfl_down(r2, d);
      dp += __shfl_down(dp, d);
      ac += __shfl_down(ac, d);
    }
    if (j == 0) {
      float bg = 1.f - ac;
      out[ray * 3 + 0] = r0 + bg;
      out[ray * 3 + 1] = r1 + bg;
      out[ray * 3 + 2] = r2 + bg;
      out[NRAYS * 3 + ray] = dp;
      out[NRAYS * 4 + ray] = ac;
    }
  }
}

extern "C" void kernel_launch(void* const* d_in, const int* in_sizes, int n_in,
                              void* d_out, int out_size, void* d_ws, size_t ws_size,
                              hipStream_t stream) {
  const float* rays_o = (const float*)d_in[0];
  const float* rays_d = (const float*)d_in[1];
  const float* t_rand = (const float*)d_in[2];
  const float* W1 = (const float*)d_in[3];
  const float* b1 = (const float*)d_in[4];
  const float* W2 = (const float*)d_in[5];
  const float* b2 = (const float*)d_in[6];
  const float* W3 = (const float*)d_in[7];
  const float* b3 = (const float*)d_in[8];
  const float* Wd = (const float*)d_in[9];
  const float* bd = (const float*)d_in[10];
  const float* W4 = (const float*)d_in[11];
  const float* b4 = (const float*)d_in[12];
  const float* W5 = (const float*)d_in[13];
  const float* b5 = (const float*)d_in[14];
  u16* wpack = (u16*)d_ws;
  float* out = (float*)d_out;

  pack_weights<<<640, 256, 0, stream>>>(W2, W3, W4, wpack);
  nerf_fused<<<NRAYS, 256, 0, stream>>>(rays_o, rays_d, t_rand, W1, b1, b2, b3,
                                        Wd, bd, W4, b4, W5, b5, wpack, out);
}

// Round 9
// 508.208 us; speedup vs baseline: 1.1107x; 1.0361x over previous
//
#include <hip/hip_runtime.h>
#include <stdint.h>

// R9: fit the 128-reg budget BY CONSTRUCTION (R7/R8 showed any budget <192
// spills because full kc-unroll hoists 32 B-loads = 128 VGPRs):
//  - wave tile 2x4 (acc 32 regs), layers done in two row-passes (rows 0-31 /
//    32-63, disjoint in-place act updates, 2 barriers/layer)
//  - #pragma unroll 2 on kc: only 8 B-loads in flight (32 regs)
//  - __launch_bounds__(256,4): 16 waves/CU, 4 co-resident blocks (2x R6 TLP)
// Sentinel: WRITE_SIZE <5 MB = no spill; >50 MB = revert.

#define NRAYS 4096

typedef unsigned short u16;
typedef __attribute__((ext_vector_type(8))) short short8;
typedef __attribute__((ext_vector_type(4))) float f32x4;

__device__ __forceinline__ u16 f2bf(float f) {
  union { float f; uint32_t i; } v; v.f = f;
  return (u16)((v.i + 0x7FFFu + ((v.i >> 16) & 1u)) >> 16);
}
__device__ __forceinline__ float bf2f(u16 u) {
  union { uint32_t i; float f; } v; v.i = ((uint32_t)u) << 16; return v.f;
}

// ---------------- weight transpose + fp32->bf16 convert into workspace ----------------
// ws (bf16 elems): W2t [256n][256k] @0, W3t [256n][256k] @65536, W4t [128n][256k] @131072
__global__ void pack_weights(const float* __restrict__ W2, const float* __restrict__ W3,
                             const float* __restrict__ W4, u16* __restrict__ ws) {
  int idx = blockIdx.x * 256 + threadIdx.x;   // grid covers exactly 163840
  float v;
  if (idx < 65536) {
    int n = idx >> 8, k = idx & 255;
    v = W2[k * 256 + n];
  } else if (idx < 131072) {
    int o = idx - 65536, n = o >> 8, k = o & 255;
    v = W3[k * 256 + n];
  } else {
    int o = idx - 131072, n = o >> 8, k = o & 255;
    v = W4[k * 128 + n];
  }
  ws[idx] = f2bf(v);
}

#define MFMA __builtin_amdgcn_mfma_f32_16x16x32_bf16
#define ZER4 (f32x4){0.f, 0.f, 0.f, 0.f}

// K-step, 2 row-tiles x 4 col-tiles: 4 B (global), 2 A (LDS), 8 MFMA
#define KSTEP42(sq_) do {                                                    \
    const int sq = (sq_);                                                    \
    short8 bv0 = *(const short8*)(bp0 + sq * 8);                             \
    short8 bv1 = *(const short8*)(bp1 + sq * 8);                             \
    short8 bv2 = *(const short8*)(bp2 + sq * 8);                             \
    short8 bv3 = *(const short8*)(bp3 + sq * 8);                             \
    short8 av0 = *(const short8*)(act + m0 * 256 + ((sq ^ (m0 & 31)) << 3)); \
    short8 av1 = *(const short8*)(act + m1 * 256 + ((sq ^ (m1 & 31)) << 3)); \
    c00 = MFMA(av0, bv0, c00, 0, 0, 0); c10 = MFMA(av1, bv0, c10, 0, 0, 0);  \
    c01 = MFMA(av0, bv1, c01, 0, 0, 0); c11 = MFMA(av1, bv1, c11, 0, 0, 0);  \
    c02 = MFMA(av0, bv2, c02, 0, 0, 0); c12 = MFMA(av1, bv2, c12, 0, 0, 0);  \
    c03 = MFMA(av0, bv3, c03, 0, 0, 0); c13 = MFMA(av1, bv3, c13, 0, 0, 0);  \
  } while (0)

// K-step, 2 row-tiles x 2 col-tiles (layer 4): 2 B, 2 A, 4 MFMA
#define KSTEP22(sq_) do {                                                    \
    const int sq = (sq_);                                                    \
    short8 bv0 = *(const short8*)(bp0 + sq * 8);                             \
    short8 bv1 = *(const short8*)(bp1 + sq * 8);                             \
    short8 av0 = *(const short8*)(act + m0 * 256 + ((sq ^ (m0 & 31)) << 3)); \
    short8 av1 = *(const short8*)(act + m1 * 256 + ((sq ^ (m1 & 31)) << 3)); \
    c00 = MFMA(av0, bv0, c00, 0, 0, 0); c10 = MFMA(av1, bv0, c10, 0, 0, 0);  \
    c01 = MFMA(av0, bv1, c01, 0, 0, 0); c11 = MFMA(av1, bv1, c11, 0, 0, 0);  \
  } while (0)

// store one 16x16 C-tile (named f32x4 CV), absolute row-tile mta, column ng
#define EPIC(CV, mta, ng, addv) do {                                         \
    int su_ = ((ng) >> 3), so_ = ((ng) & 7);                                 \
    _Pragma("unroll")                                                        \
    for (int rr = 0; rr < 4; rr++) {                                         \
      int mm = (mta) * 16 + quad * 4 + rr;                                   \
      act[mm * 256 + ((su_ ^ (mm & 31)) << 3) + so_] =                       \
          f2bf(fmaxf((CV)[rr] + (addv), 0.f));                               \
    }                                                                        \
  } while (0)

__global__ void __launch_bounds__(256, 4) nerf_fused(
    const float* __restrict__ rays_o, const float* __restrict__ rays_d,
    const float* __restrict__ t_rand,
    const float* __restrict__ W1, const float* __restrict__ b1,
    const float* __restrict__ b2, const float* __restrict__ b3,
    const float* __restrict__ Wd, const float* __restrict__ bd,
    const float* __restrict__ W4, const float* __restrict__ b4,
    const float* __restrict__ W5, const float* __restrict__ b5,
    const u16* __restrict__ wpack, float* __restrict__ out) {
  __shared__ u16   act[64 * 256];    // 32 KB, XOR-swizzled slots
  __shared__ float zv[64];
  __shared__ float dist[64];
  __shared__ float dens[64];
  __shared__ float rgbL[64 * 4];
  __shared__ float vdirL[4];
  __shared__ float w5L[384];
  __shared__ float b5L[4];

  const int t = threadIdx.x;
  const int lane = t & 63;
  const int cq = t >> 6;        // 0..3 : col quarter (wave id)
  const int quad = lane >> 4;
  const int l15 = lane & 15;
  const int ray = blockIdx.x;

  // ---- setup ----
  if (t < 64) {
    int j = t;
    float fj = (float)j;
    float zj = 0.5f + 2.0f * (fj / 63.0f);
    float lower = (j == 0)  ? zj : 0.5f * (zj + (0.5f + 2.0f * ((fj - 1.0f) / 63.0f)));
    float upper = (j == 63) ? zj : 0.5f * (zj + (0.5f + 2.0f * ((fj + 1.0f) / 63.0f)));
    float tr = t_rand[ray * 64 + j];
    zv[j] = lower + (upper - lower) * tr;
  } else {
    int idx = t - 64;                 // 0..191
    w5L[idx] = W5[idx];
    w5L[idx + 192] = W5[idx + 192];
  }
  if (t < 3) b5L[t] = b5[t];
  if (t == 0) {
    float dx = rays_d[ray * 3 + 0];
    float dy = rays_d[ray * 3 + 1];
    float dz = rays_d[ray * 3 + 2];
    float nrm = sqrtf(dx * dx + dy * dy + dz * dz) + 1e-8f;
    vdirL[0] = dx / nrm; vdirL[1] = dy / nrm; vdirL[2] = dz / nrm;
  }
  __syncthreads();                   // B0

  if (t < 64) dist[t] = (t < 63) ? (zv[t + 1] - zv[t]) : 1e10f;

  // ---- layer 1: h1 = relu(pts@W1 + b1) -> act ----
  {
    int m = t >> 2, p = t & 3;
    float zm = zv[m];
    float px = rays_o[ray * 3 + 0] + rays_d[ray * 3 + 0] * zm;
    float py = rays_o[ray * 3 + 1] + rays_d[ray * 3 + 1] * zm;
    float pz = rays_o[ray * 3 + 2] + rays_d[ray * 3 + 2] * zm;
#pragma unroll
    for (int kk = 0; kk < 64; kk += 8) {
      int k0 = p * 64 + kk;
      f32x4 bva = *(const f32x4*)(b1 + k0);
      f32x4 bvb = *(const f32x4*)(b1 + k0 + 4);
      f32x4 w0a = *(const f32x4*)(W1 + k0);
      f32x4 w0b = *(const f32x4*)(W1 + k0 + 4);
      f32x4 w1a = *(const f32x4*)(W1 + 256 + k0);
      f32x4 w1b = *(const f32x4*)(W1 + 256 + k0 + 4);
      f32x4 w2a = *(const f32x4*)(W1 + 512 + k0);
      f32x4 w2b = *(const f32x4*)(W1 + 512 + k0 + 4);
      f32x4 sa = bva + px * w0a + py * w1a + pz * w2a;
      f32x4 sb = bvb + px * w0b + py * w1b + pz * w2b;
      short8 res;
      res[0] = (short)f2bf(fmaxf(sa[0], 0.f));
      res[1] = (short)f2bf(fmaxf(sa[1], 0.f));
      res[2] = (short)f2bf(fmaxf(sa[2], 0.f));
      res[3] = (short)f2bf(fmaxf(sa[3], 0.f));
      res[4] = (short)f2bf(fmaxf(sb[0], 0.f));
      res[5] = (short)f2bf(fmaxf(sb[1], 0.f));
      res[6] = (short)f2bf(fmaxf(sb[2], 0.f));
      res[7] = (short)f2bf(fmaxf(sb[3], 0.f));
      int u = (k0 >> 3) ^ (m & 31);
      *(short8*)(act + m * 256 + u * 8) = res;
    }
  }
  __syncthreads();                   // B1: act = h1

  // ---- layers 2 & 3: two row-passes each, in-place act, 2 barriers/layer ----
#pragma unroll 1
  for (int L = 0; L < 2; L++) {
    const u16* wB = wpack + L * 65536;
    const float* bb = (L == 0) ? b2 : b3;
    const u16* bp0 = wB + (cq * 64 +  0 + l15) * 256;
    const u16* bp1 = wB + (cq * 64 + 16 + l15) * 256;
    const u16* bp2 = wB + (cq * 64 + 32 + l15) * 256;
    const u16* bp3 = wB + (cq * 64 + 48 + l15) * 256;
#pragma unroll 1
    for (int r = 0; r < 2; r++) {
      const int m0 = r * 32 + l15, m1 = m0 + 16;
      f32x4 c00 = ZER4, c01 = ZER4, c02 = ZER4, c03 = ZER4;
      f32x4 c10 = ZER4, c11 = ZER4, c12 = ZER4, c13 = ZER4;
#pragma unroll 2
      for (int kc = 0; kc < 8; kc++) KSTEP42(kc * 4 + quad);
      __syncthreads();               // all reads of this row-half done
      {
        int ng0 = cq * 64 + l15;
        float bi0 = bb[ng0], bi1 = bb[ng0 + 16], bi2 = bb[ng0 + 32], bi3 = bb[ng0 + 48];
        int t0 = r * 2, t1 = r * 2 + 1;
        EPIC(c00, t0, ng0, bi0);      EPIC(c10, t1, ng0, bi0);
        EPIC(c01, t0, ng0 + 16, bi1); EPIC(c11, t1, ng0 + 16, bi1);
        EPIC(c02, t0, ng0 + 32, bi2); EPIC(c12, t1, ng0 + 32, bi2);
        EPIC(c03, t0, ng0 + 48, bi3); EPIC(c13, t1, ng0 + 48, bi3);
      }
      // no barrier after epilogue: next pass reads the OTHER row-half
    }
  }
  __syncthreads();                   // B_postL3: act = h3 complete

  // ---- density: fp32 dot(h3, Wd), all rows ----
  {
    int m = t >> 2, p = t & 3;
    float s = 0.f;
#pragma unroll
    for (int kk = 0; kk < 64; kk += 8) {
      int k0 = p * 64 + kk;
      short8 h = *(const short8*)(act + m * 256 + (((k0 >> 3) ^ (m & 31)) << 3));
      f32x4 wa = *(const f32x4*)(Wd + k0);
      f32x4 wb = *(const f32x4*)(Wd + k0 + 4);
      s += bf2f((u16)h[0]) * wa[0] + bf2f((u16)h[1]) * wa[1]
         + bf2f((u16)h[2]) * wa[2] + bf2f((u16)h[3]) * wa[3]
         + bf2f((u16)h[4]) * wb[0] + bf2f((u16)h[5]) * wb[1]
         + bf2f((u16)h[6]) * wb[2] + bf2f((u16)h[7]) * wb[3];
    }
    s += __shfl_xor(s, 1);
    s += __shfl_xor(s, 2);
    if (p == 0) dens[m] = s + bd[0];
  }

  // ---- layer 4: h4 = relu(h3@W4[:256] + vdir-tail + b4), N=128, two row-passes ----
  {
    const u16* wB = wpack + 131072;
    const u16* bp0 = wB + (cq * 32 +  0 + l15) * 256;
    const u16* bp1 = wB + (cq * 32 + 16 + l15) * 256;
    float v0 = vdirL[0], v1 = vdirL[1], v2 = vdirL[2];
    int ng0 = cq * 32 + l15;
    float ad0 = b4[ng0] + v0 * W4[32768 + ng0] + v1 * W4[32896 + ng0] + v2 * W4[33024 + ng0];
    int ng1 = ng0 + 16;
    float ad1 = b4[ng1] + v0 * W4[32768 + ng1] + v1 * W4[32896 + ng1] + v2 * W4[33024 + ng1];
#pragma unroll 1
    for (int r = 0; r < 2; r++) {
      const int m0 = r * 32 + l15, m1 = m0 + 16;
      f32x4 c00 = ZER4, c01 = ZER4;
      f32x4 c10 = ZER4, c11 = ZER4;
#pragma unroll 2
      for (int kc = 0; kc < 8; kc++) KSTEP22(kc * 4 + quad);
      __syncthreads();               // density + this row-half reads done
      {
        int t0 = r * 2, t1 = r * 2 + 1;
        EPIC(c00, t0, ng0, ad0); EPIC(c10, t1, ng0, ad0);
        EPIC(c01, t0, ng1, ad1); EPIC(c11, t1, ng1, ad1);
      }
    }
  }
  __syncthreads();                   // B_postL4: act = h4

  // ---- rgb = sigmoid(h4@W5 + b5) ----
  {
    int m = t >> 2, p = t & 3;
    float s0 = 0.f, s1 = 0.f, s2 = 0.f;
#pragma unroll
    for (int kk = 0; kk < 32; kk += 8) {
      int k0 = p * 32 + kk;
      short8 h = *(const short8*)(act + m * 256 + (((k0 >> 3) ^ (m & 31)) << 3));
#pragma unroll
      for (int j = 0; j < 8; j++) {
        float hv = bf2f((u16)h[j]);
        int k = k0 + j;
        s0 += hv * w5L[k * 3 + 0];
        s1 += hv * w5L[k * 3 + 1];
        s2 += hv * w5L[k * 3 + 2];
      }
    }
    s0 += __shfl_xor(s0, 1); s0 += __shfl_xor(s0, 2);
    s1 += __shfl_xor(s1, 1); s1 += __shfl_xor(s1, 2);
    s2 += __shfl_xor(s2, 1); s2 += __shfl_xor(s2, 2);
    if (p == 0) {
      rgbL[m * 4 + 0] = 1.f / (1.f + __expf(-(s0 + b5L[0])));
      rgbL[m * 4 + 1] = 1.f / (1.f + __expf(-(s1 + b5L[1])));
      rgbL[m * 4 + 2] = 1.f / (1.f + __expf(-(s2 + b5L[2])));
    }
  }
  __syncthreads();                   // B_rgb

  // ---- alpha compositing: wave 0 ----
  if (t < 64) {
    int j = t;
    float alpha = 1.f - __expf(-fmaxf(dens[j], 0.f) * dist[j]);
    float v = 1.f - alpha + 1e-10f;
    float pscan = v;
#pragma unroll
    for (int d = 1; d < 64; d <<= 1) {
      float o = __shfl_up(pscan, d);
      if (j >= d) pscan *= o;
    }
    float T = __shfl_up(pscan, 1);
    if (j == 0) T = 1.f;
    float w = alpha * T;
    float r0 = w * rgbL[j * 4 + 0];
    float r1 = w * rgbL[j * 4 + 1];
    float r2 = w * rgbL[j * 4 + 2];
    float dp = w * zv[j];
    float ac = w;
#pragma unroll
    for (int d = 32; d; d >>= 1) {
      r0 += __shfl_down(r0, d);
      r1 += __shfl_down(r1, d);
      r2 += __shfl_down(r2, d);
      dp += __shfl_down(dp, d);
      ac += __shfl_down(ac, d);
    }
    if (j == 0) {
      float bg = 1.f - ac;
      out[ray * 3 + 0] = r0 + bg;
      out[ray * 3 + 1] = r1 + bg;
      out[ray * 3 + 2] = r2 + bg;
      out[NRAYS * 3 + ray] = dp;
      out[NRAYS * 4 + ray] = ac;
    }
  }
}

extern "C" void kernel_launch(void* const* d_in, const int* in_sizes, int n_in,
                              void* d_out, int out_size, void* d_ws, size_t ws_size,
                              hipStream_t stream) {
  const float* rays_o = (const float*)d_in[0];
  const float* rays_d = (const float*)d_in[1];
  const float* t_rand = (const float*)d_in[2];
  const float* W1 = (const float*)d_in[3];
  const float* b1 = (const float*)d_in[4];
  const float* W2 = (const float*)d_in[5];
  const float* b2 = (const float*)d_in[6];
  const float* W3 = (const float*)d_in[7];
  const float* b3 = (const float*)d_in[8];
  const float* Wd = (const float*)d_in[9];
  const float* bd = (const float*)d_in[10];
  const float* W4 = (const float*)d_in[11];
  const float* b4 = (const float*)d_in[12];
  const float* W5 = (const float*)d_in[13];
  const float* b5 = (const float*)d_in[14];
  u16* wpack = (u16*)d_ws;
  float* out = (float*)d_out;

  pack_weights<<<640, 256, 0, stream>>>(W2, W3, W4, wpack);
  nerf_fused<<<NRAYS, 256, 0, stream>>>(rays_o, rays_d, t_rand, W1, b1, b2, b3,
                                        Wd, bd, W4, b4, W5, b5, wpack, out);
}

// Round 10
// 471.409 us; speedup vs baseline: 1.1974x; 1.0781x over previous
//
#include <hip/hip_runtime.h>
#include <stdint.h>

// R10: R6 (best, 333us) with exactly two changes:
//  - __launch_bounds__(256,3): 170-reg budget -> 12 waves/CU (1.5x R6)
//  - #pragma unroll 4 on kc loops: 16 B-loads hoisted (64 VGPRs) instead of 32
//    (128) -> demand ~169 fits 170. R6<->R9 proved pipelining depth > occupancy;
//    this keeps near-R6 depth (2 stalls/layer) at 1.5x the waves.
// Sentinels: WRITE_SIZE <5MB = fits; >50MB = spill, revert & pivot to LDS-B.

#define NRAYS 4096

typedef unsigned short u16;
typedef __attribute__((ext_vector_type(8))) short short8;
typedef __attribute__((ext_vector_type(4))) float f32x4;

__device__ __forceinline__ u16 f2bf(float f) {
  union { float f; uint32_t i; } v; v.f = f;
  return (u16)((v.i + 0x7FFFu + ((v.i >> 16) & 1u)) >> 16);
}
__device__ __forceinline__ float bf2f(u16 u) {
  union { uint32_t i; float f; } v; v.i = ((uint32_t)u) << 16; return v.f;
}

// ---------------- weight transpose + fp32->bf16 convert into workspace ----------------
// ws (bf16 elems): W2t [256n][256k] @0, W3t [256n][256k] @65536, W4t [128n][256k] @131072
__global__ void pack_weights(const float* __restrict__ W2, const float* __restrict__ W3,
                             const float* __restrict__ W4, u16* __restrict__ ws) {
  int idx = blockIdx.x * 256 + threadIdx.x;   // grid covers exactly 163840
  float v;
  if (idx < 65536) {
    int n = idx >> 8, k = idx & 255;
    v = W2[k * 256 + n];
  } else if (idx < 131072) {
    int o = idx - 65536, n = o >> 8, k = o & 255;
    v = W3[k * 256 + n];
  } else {
    int o = idx - 131072, n = o >> 8, k = o & 255;
    v = W4[k * 128 + n];
  }
  ws[idx] = f2bf(v);
}

#define MFMA __builtin_amdgcn_mfma_f32_16x16x32_bf16
#define ZER4 (f32x4){0.f, 0.f, 0.f, 0.f}

// one K-step (K=32) of the 4-col-tile GEMM: 4 B loads (global), 4 A loads (LDS), 16 MFMA
#define KSTEP4(sq_) do {                                                     \
    const int sq = (sq_);                                                    \
    short8 bv0 = *(const short8*)(bp0 + sq * 8);                             \
    short8 bv1 = *(const short8*)(bp1 + sq * 8);                             \
    short8 bv2 = *(const short8*)(bp2 + sq * 8);                             \
    short8 bv3 = *(const short8*)(bp3 + sq * 8);                             \
    short8 av0 = *(const short8*)(act + m0 * 256 + ((sq ^ (m0 & 31)) << 3)); \
    short8 av1 = *(const short8*)(act + m1 * 256 + ((sq ^ (m1 & 31)) << 3)); \
    short8 av2 = *(const short8*)(act + m2 * 256 + ((sq ^ (m2 & 31)) << 3)); \
    short8 av3 = *(const short8*)(act + m3 * 256 + ((sq ^ (m3 & 31)) << 3)); \
    c00 = MFMA(av0, bv0, c00, 0, 0, 0); c10 = MFMA(av1, bv0, c10, 0, 0, 0);  \
    c20 = MFMA(av2, bv0, c20, 0, 0, 0); c30 = MFMA(av3, bv0, c30, 0, 0, 0);  \
    c01 = MFMA(av0, bv1, c01, 0, 0, 0); c11 = MFMA(av1, bv1, c11, 0, 0, 0);  \
    c21 = MFMA(av2, bv1, c21, 0, 0, 0); c31 = MFMA(av3, bv1, c31, 0, 0, 0);  \
    c02 = MFMA(av0, bv2, c02, 0, 0, 0); c12 = MFMA(av1, bv2, c12, 0, 0, 0);  \
    c22 = MFMA(av2, bv2, c22, 0, 0, 0); c32 = MFMA(av3, bv2, c32, 0, 0, 0);  \
    c03 = MFMA(av0, bv3, c03, 0, 0, 0); c13 = MFMA(av1, bv3, c13, 0, 0, 0);  \
    c23 = MFMA(av2, bv3, c23, 0, 0, 0); c33 = MFMA(av3, bv3, c33, 0, 0, 0);  \
  } while (0)

// one K-step of the 2-col-tile GEMM (layer 4)
#define KSTEP2(sq_) do {                                                     \
    const int sq = (sq_);                                                    \
    short8 bv0 = *(const short8*)(bp0 + sq * 8);                             \
    short8 bv1 = *(const short8*)(bp1 + sq * 8);                             \
    short8 av0 = *(const short8*)(act + m0 * 256 + ((sq ^ (m0 & 31)) << 3)); \
    short8 av1 = *(const short8*)(act + m1 * 256 + ((sq ^ (m1 & 31)) << 3)); \
    short8 av2 = *(const short8*)(act + m2 * 256 + ((sq ^ (m2 & 31)) << 3)); \
    short8 av3 = *(const short8*)(act + m3 * 256 + ((sq ^ (m3 & 31)) << 3)); \
    c00 = MFMA(av0, bv0, c00, 0, 0, 0); c10 = MFMA(av1, bv0, c10, 0, 0, 0);  \
    c20 = MFMA(av2, bv0, c20, 0, 0, 0); c30 = MFMA(av3, bv0, c30, 0, 0, 0);  \
    c01 = MFMA(av0, bv1, c01, 0, 0, 0); c11 = MFMA(av1, bv1, c11, 0, 0, 0);  \
    c21 = MFMA(av2, bv1, c21, 0, 0, 0); c31 = MFMA(av3, bv1, c31, 0, 0, 0);  \
  } while (0)

// store one 16x16 C-tile (named f32x4 CV), row-tile mt, column ng, into swizzled act
#define EPIC(CV, mt, ng, addv) do {                                          \
    int su_ = ((ng) >> 3), so_ = ((ng) & 7);                                 \
    _Pragma("unroll")                                                        \
    for (int r = 0; r < 4; r++) {                                            \
      int mm = (mt) * 16 + quad * 4 + r;                                     \
      act[mm * 256 + ((su_ ^ (mm & 31)) << 3) + so_] =                       \
          f2bf(fmaxf((CV)[r] + (addv), 0.f));                                \
    }                                                                        \
  } while (0)

__global__ void __launch_bounds__(256, 3) nerf_fused(
    const float* __restrict__ rays_o, const float* __restrict__ rays_d,
    const float* __restrict__ t_rand,
    const float* __restrict__ W1, const float* __restrict__ b1,
    const float* __restrict__ b2, const float* __restrict__ b3,
    const float* __restrict__ Wd, const float* __restrict__ bd,
    const float* __restrict__ W4, const float* __restrict__ b4,
    const float* __restrict__ W5, const float* __restrict__ b5,
    const u16* __restrict__ wpack, float* __restrict__ out) {
  __shared__ u16   act[64 * 256];    // 32 KB, XOR-swizzled slots
  __shared__ float zv[64];
  __shared__ float dist[64];
  __shared__ float dens[64];
  __shared__ float rgbL[64 * 4];
  __shared__ float vdirL[4];
  __shared__ float w5L[384];
  __shared__ float b5L[4];

  const int t = threadIdx.x;
  const int lane = t & 63;
  const int wv = t >> 6;        // 0..3
  const int quad = lane >> 4;
  const int l15 = lane & 15;
  const int ray = blockIdx.x;
  const int m0 = l15, m1 = l15 + 16, m2 = l15 + 32, m3 = l15 + 48;

  // ---- setup ----
  if (t < 64) {
    int j = t;
    float fj = (float)j;
    float zj = 0.5f + 2.0f * (fj / 63.0f);
    float lower = (j == 0)  ? zj : 0.5f * (zj + (0.5f + 2.0f * ((fj - 1.0f) / 63.0f)));
    float upper = (j == 63) ? zj : 0.5f * (zj + (0.5f + 2.0f * ((fj + 1.0f) / 63.0f)));
    float tr = t_rand[ray * 64 + j];
    zv[j] = lower + (upper - lower) * tr;
  } else {
    int idx = t - 64;                 // 0..191
    w5L[idx] = W5[idx];
    w5L[idx + 192] = W5[idx + 192];
  }
  if (t < 3) b5L[t] = b5[t];
  if (t == 0) {
    float dx = rays_d[ray * 3 + 0];
    float dy = rays_d[ray * 3 + 1];
    float dz = rays_d[ray * 3 + 2];
    float nrm = sqrtf(dx * dx + dy * dy + dz * dz) + 1e-8f;
    vdirL[0] = dx / nrm; vdirL[1] = dy / nrm; vdirL[2] = dz / nrm;
  }
  __syncthreads();

  if (t < 64) dist[t] = (t < 63) ? (zv[t + 1] - zv[t]) : 1e10f;

  // ---- layer 1: h1 = relu(pts@W1 + b1) -> act (pure vector ops) ----
  {
    int m = t >> 2, p = t & 3;
    float zm = zv[m];
    float px = rays_o[ray * 3 + 0] + rays_d[ray * 3 + 0] * zm;
    float py = rays_o[ray * 3 + 1] + rays_d[ray * 3 + 1] * zm;
    float pz = rays_o[ray * 3 + 2] + rays_d[ray * 3 + 2] * zm;
#pragma unroll
    for (int kk = 0; kk < 64; kk += 8) {
      int k0 = p * 64 + kk;
      f32x4 bva = *(const f32x4*)(b1 + k0);
      f32x4 bvb = *(const f32x4*)(b1 + k0 + 4);
      f32x4 w0a = *(const f32x4*)(W1 + k0);
      f32x4 w0b = *(const f32x4*)(W1 + k0 + 4);
      f32x4 w1a = *(const f32x4*)(W1 + 256 + k0);
      f32x4 w1b = *(const f32x4*)(W1 + 256 + k0 + 4);
      f32x4 w2a = *(const f32x4*)(W1 + 512 + k0);
      f32x4 w2b = *(const f32x4*)(W1 + 512 + k0 + 4);
      f32x4 sa = bva + px * w0a + py * w1a + pz * w2a;
      f32x4 sb = bvb + px * w0b + py * w1b + pz * w2b;
      short8 res;
      res[0] = (short)f2bf(fmaxf(sa[0], 0.f));
      res[1] = (short)f2bf(fmaxf(sa[1], 0.f));
      res[2] = (short)f2bf(fmaxf(sa[2], 0.f));
      res[3] = (short)f2bf(fmaxf(sa[3], 0.f));
      res[4] = (short)f2bf(fmaxf(sb[0], 0.f));
      res[5] = (short)f2bf(fmaxf(sb[1], 0.f));
      res[6] = (short)f2bf(fmaxf(sb[2], 0.f));
      res[7] = (short)f2bf(fmaxf(sb[3], 0.f));
      int u = (k0 >> 3) ^ (m & 31);
      *(short8*)(act + m * 256 + u * 8) = res;
    }
  }
  __syncthreads();

  // ---- layers 2 & 3: h = relu(h@W + b), K=256, N=256, B streamed from L2 ----
#pragma unroll 1
  for (int L = 0; L < 2; L++) {
    const u16* wB = wpack + L * 65536;
    const float* bb = (L == 0) ? b2 : b3;
    const u16* bp0 = wB + (wv * 64 +  0 + l15) * 256;
    const u16* bp1 = wB + (wv * 64 + 16 + l15) * 256;
    const u16* bp2 = wB + (wv * 64 + 32 + l15) * 256;
    const u16* bp3 = wB + (wv * 64 + 48 + l15) * 256;
    f32x4 c00 = ZER4, c01 = ZER4, c02 = ZER4, c03 = ZER4;
    f32x4 c10 = ZER4, c11 = ZER4, c12 = ZER4, c13 = ZER4;
    f32x4 c20 = ZER4, c21 = ZER4, c22 = ZER4, c23 = ZER4;
    f32x4 c30 = ZER4, c31 = ZER4, c32 = ZER4, c33 = ZER4;
#pragma unroll 4
    for (int kc = 0; kc < 8; kc++) KSTEP4(kc * 4 + quad);
    __syncthreads();               // all act reads done before in-place rewrite
    {
      int ng0 = wv * 64 + l15;
      float bi0 = bb[ng0], bi1 = bb[ng0 + 16], bi2 = bb[ng0 + 32], bi3 = bb[ng0 + 48];
      EPIC(c00, 0, ng0, bi0); EPIC(c10, 1, ng0, bi0);
      EPIC(c20, 2, ng0, bi0); EPIC(c30, 3, ng0, bi0);
      EPIC(c01, 0, ng0 + 16, bi1); EPIC(c11, 1, ng0 + 16, bi1);
      EPIC(c21, 2, ng0 + 16, bi1); EPIC(c31, 3, ng0 + 16, bi1);
      EPIC(c02, 0, ng0 + 32, bi2); EPIC(c12, 1, ng0 + 32, bi2);
      EPIC(c22, 2, ng0 + 32, bi2); EPIC(c32, 3, ng0 + 32, bi2);
      EPIC(c03, 0, ng0 + 48, bi3); EPIC(c13, 1, ng0 + 48, bi3);
      EPIC(c23, 2, ng0 + 48, bi3); EPIC(c33, 3, ng0 + 48, bi3);
    }
    __syncthreads();
  }

  // ---- density: fp32 dot(h3, Wd) ----
  {
    int m = t >> 2, p = t & 3;
    float s = 0.f;
#pragma unroll
    for (int kk = 0; kk < 64; kk += 8) {
      int k0 = p * 64 + kk;
      short8 h = *(const short8*)(act + m * 256 + (((k0 >> 3) ^ (m & 31)) << 3));
      f32x4 wa = *(const f32x4*)(Wd + k0);
      f32x4 wb = *(const f32x4*)(Wd + k0 + 4);
      s += bf2f((u16)h[0]) * wa[0] + bf2f((u16)h[1]) * wa[1]
         + bf2f((u16)h[2]) * wa[2] + bf2f((u16)h[3]) * wa[3]
         + bf2f((u16)h[4]) * wb[0] + bf2f((u16)h[5]) * wb[1]
         + bf2f((u16)h[6]) * wb[2] + bf2f((u16)h[7]) * wb[3];
    }
    s += __shfl_xor(s, 1);
    s += __shfl_xor(s, 2);
    if (p == 0) dens[m] = s + bd[0];
  }

  // ---- layer 4: h4 = relu(h3@W4[:256] + vdir@W4[256:259] + b4), N=128 ----
  {
    const u16* wB = wpack + 131072;
    const u16* bp0 = wB + (wv * 32 +  0 + l15) * 256;
    const u16* bp1 = wB + (wv * 32 + 16 + l15) * 256;
    f32x4 c00 = ZER4, c01 = ZER4;
    f32x4 c10 = ZER4, c11 = ZER4;
    f32x4 c20 = ZER4, c21 = ZER4;
    f32x4 c30 = ZER4, c31 = ZER4;
#pragma unroll 4
    for (int kc = 0; kc < 8; kc++) KSTEP2(kc * 4 + quad);
    __syncthreads();               // all h3 reads done (incl. density) before rewrite
    {
      float v0 = vdirL[0], v1 = vdirL[1], v2 = vdirL[2];
      int ng0 = wv * 32 + l15;
      float ad0 = b4[ng0] + v0 * W4[32768 + ng0] + v1 * W4[32896 + ng0] + v2 * W4[33024 + ng0];
      int ng1 = ng0 + 16;
      float ad1 = b4[ng1] + v0 * W4[32768 + ng1] + v1 * W4[32896 + ng1] + v2 * W4[33024 + ng1];
      EPIC(c00, 0, ng0, ad0); EPIC(c10, 1, ng0, ad0);
      EPIC(c20, 2, ng0, ad0); EPIC(c30, 3, ng0, ad0);
      EPIC(c01, 0, ng1, ad1); EPIC(c11, 1, ng1, ad1);
      EPIC(c21, 2, ng1, ad1); EPIC(c31, 3, ng1, ad1);
    }
  }
  __syncthreads();

  // ---- rgb = sigmoid(h4@W5 + b5) ----
  {
    int m = t >> 2, p = t & 3;
    float s0 = 0.f, s1 = 0.f, s2 = 0.f;
#pragma unroll
    for (int kk = 0; kk < 32; kk += 8) {
      int k0 = p * 32 + kk;
      short8 h = *(const short8*)(act + m * 256 + (((k0 >> 3) ^ (m & 31)) << 3));
#pragma unroll
      for (int j = 0; j < 8; j++) {
        float hv = bf2f((u16)h[j]);
        int k = k0 + j;
        s0 += hv * w5L[k * 3 + 0];
        s1 += hv * w5L[k * 3 + 1];
        s2 += hv * w5L[k * 3 + 2];
      }
    }
    s0 += __shfl_xor(s0, 1); s0 += __shfl_xor(s0, 2);
    s1 += __shfl_xor(s1, 1); s1 += __shfl_xor(s1, 2);
    s2 += __shfl_xor(s2, 1); s2 += __shfl_xor(s2, 2);
    if (p == 0) {
      rgbL[m * 4 + 0] = 1.f / (1.f + __expf(-(s0 + b5L[0])));
      rgbL[m * 4 + 1] = 1.f / (1.f + __expf(-(s1 + b5L[1])));
      rgbL[m * 4 + 2] = 1.f / (1.f + __expf(-(s2 + b5L[2])));
    }
  }
  __syncthreads();

  // ---- alpha compositing: wave 0 handles the block's single ray ----
  if (t < 64) {
    int j = t;
    float alpha = 1.f - __expf(-fmaxf(dens[j], 0.f) * dist[j]);
    float v = 1.f - alpha + 1e-10f;
    float pscan = v;
#pragma unroll
    for (int d = 1; d < 64; d <<= 1) {
      float o = __shfl_up(pscan, d);
      if (j >= d) pscan *= o;
    }
    float T = __shfl_up(pscan, 1);
    if (j == 0) T = 1.f;
    float w = alpha * T;
    float r0 = w * rgbL[j * 4 + 0];
    float r1 = w * rgbL[j * 4 + 1];
    float r2 = w * rgbL[j * 4 + 2];
    float dp = w * zv[j];
    float ac = w;
#pragma unroll
    for (int d = 32; d; d >>= 1) {
      r0 += __shfl_down(r0, d);
      r1 += __shfl_down(r1, d);
      r2 += __shfl_down(r2, d);
      dp += __shfl_down(dp, d);
      ac += __shfl_down(ac, d);
    }
    if (j == 0) {
      float bg = 1.f - ac;
      out[ray * 3 + 0] = r0 + bg;
      out[ray * 3 + 1] = r1 + bg;
      out[ray * 3 + 2] = r2 + bg;
      out[NRAYS * 3 + ray] = dp;
      out[NRAYS * 4 + ray] = ac;
    }
  }
}

extern "C" void kernel_launch(void* const* d_in, const int* in_sizes, int n_in,
                              void* d_out, int out_size, void* d_ws, size_t ws_size,
                              hipStream_t stream) {
  const float* rays_o = (const float*)d_in[0];
  const float* rays_d = (const float*)d_in[1];
  const float* t_rand = (const float*)d_in[2];
  const float* W1 = (const float*)d_in[3];
  const float* b1 = (const float*)d_in[4];
  const float* W2 = (const float*)d_in[5];
  const float* b2 = (const float*)d_in[6];
  const float* W3 = (const float*)d_in[7];
  const float* b3 = (const float*)d_in[8];
  const float* Wd = (const float*)d_in[9];
  const float* bd = (const float*)d_in[10];
  const float* W4 = (const float*)d_in[11];
  const float* b4 = (const float*)d_in[12];
  const float* W5 = (const float*)d_in[13];
  const float* b5 = (const float*)d_in[14];
  u16* wpack = (u16*)d_ws;
  float* out = (float*)d_out;

  pack_weights<<<640, 256, 0, stream>>>(W2, W3, W4, wpack);
  nerf_fused<<<NRAYS, 256, 0, stream>>>(rays_o, rays_d, t_rand, W1, b1, b2, b3,
                                        Wd, bd, W4, b4, W5, b5, wpack, out);
}